// Round 4
// baseline (3385.847 us; speedup 1.0000x reference)
//
#include <hip/hip_runtime.h>
#include <math.h>

// TTT recurrence: lane = hidden index, ONE WAVE DRIVES TWO ROWS.
// R5: W2 as packed f16 pairs, v_dot2_f32_f16 matvecs, f16 LDS broadcasts.
// R7: fast_tanh (exp2+rcp), DPP wave reduction for the head.
// R8: no hot-loop barriers (single wave, DS in-order).
// R11: merged BWD->FWD phases, incremental z1.
// R12: u = w3*(1-h2^2) broadcast (dl factored), fused d-dots + w2c apply.
// R13 (reverted): readlane all-gather regressed 29% -- broadcast via
// LDS is cheaper on the issue port; latency was partially hidden.
// R14: SOFTWARE DUAL-THREADING. With 2048 waves on 1024 SIMDs the
// HW had only 2 waves/SIMD and ~60% of cycles stalled (real VALU busy
// ~40% after correcting the SIMD16-era VALUBusy formula). Now each wave
// owns TWO rows: all per-row state duplicated (w2rA/B, w2cA/B, scalars),
// the two R12-exact phase bodies interleaved in one basic block. Row B's
// dots/applies fill row A's LDS write->read gaps and vice versa --
// compile-time latency hiding with zero added instructions. Grid 1024,
// 1 wave/SIMD, __launch_bounds__(64,1) for the big register file.
// R15 (this): identical resubmit of R14 -- the R3 bench died in the
// container acquire path (no compile/test verdict), so the dual-threading
// hypothesis is still unmeasured.

#define TT  784
#define HH  64
#define LR  0.01f

typedef _Float16 h2v __attribute__((ext_vector_type(2)));
#define FDOT2(a, b, c) __builtin_amdgcn_fdot2((a), (b), (c), false)
#define BC(f) __builtin_bit_cast(h2v, (f))
#define PKFMA(acc, a, b) acc = __builtin_elementwise_fma((a), (b), (acc))

// tanh(x) = 1 - 2/(exp2(2*log2e*x)+1); saturates exactly at +-1.
__device__ __forceinline__ float fast_tanh(float x) {
    float e = __builtin_amdgcn_exp2f(x * 2.885390081777926814f);
    float r = __builtin_amdgcn_rcpf(e + 1.0f);
    return fmaf(-2.0f, r, 1.0f);
}

template <int CTRL, int RMASK, bool BC_>
__device__ __forceinline__ float dpp_add(float x) {
    int t = __builtin_amdgcn_update_dpp(0, __builtin_bit_cast(int, x),
                                        CTRL, RMASK, 0xf, BC_);
    return x + __builtin_bit_cast(float, t);
}

// Full wave64 sum -> uniform value (DPP reduce, total in lane 63).
__device__ __forceinline__ float wave_sum(float x) {
    x = dpp_add<0x111, 0xf, true>(x);   // row_shr:1
    x = dpp_add<0x112, 0xf, true>(x);   // row_shr:2
    x = dpp_add<0x114, 0xf, true>(x);   // row_shr:4
    x = dpp_add<0x118, 0xf, true>(x);   // row_shr:8
    x = dpp_add<0x142, 0xa, false>(x);  // row_bcast:15 -> rows 1,3
    x = dpp_add<0x143, 0xc, false>(x);  // row_bcast:31 -> rows 2,3
    return __builtin_bit_cast(float,
        __builtin_amdgcn_readlane(__builtin_bit_cast(int, x), 63));
}

__global__ __launch_bounds__(64, 1)
void ttt_kernel(const float* __restrict__ ts,
                const float* __restrict__ xs,
                const int*   __restrict__ mask,
                const float* __restrict__ W1,
                const float* __restrict__ b1,
                const float* __restrict__ W2,
                const float* __restrict__ b2,
                const float* __restrict__ W3,
                const float* __restrict__ b3,
                float* __restrict__ out)
{
    __shared__ __align__(16) _Float16 s_h1h[2][HH];  // h1 broadcast, f16
    __shared__ __align__(16) _Float16 s_uh[2][HH];   // u = w3*(1-h2^2), f16
    __shared__ float s_ts[TT];
    __shared__ float s_xs[2][TT];
    __shared__ float s_out[2][TT];
    __shared__ int   s_mask[2][TT - 1];

    const int rowA = 2 * blockIdx.x;
    const int rowB = rowA + 1;
    const int lane = threadIdx.x;  // 0..63

    for (int i = lane; i < TT; i += HH) {
        s_ts[i]    = ts[i];
        s_xs[0][i] = xs[rowA * TT + i];
        s_xs[1][i] = xs[rowB * TT + i];
    }
    for (int i = lane; i < TT - 1; i += HH) {
        s_mask[0][i] = mask[rowA * (TT - 1) + i];
        s_mask[1][i] = mask[rowB * (TT - 1) + i];
    }

    // Per-lane theta, duplicated per row (identical init, diverges).
    float w1aA = W1[2 * lane + 0], w1aB = w1aA;
    float w1bA = W1[2 * lane + 1], w1bB = w1bA;
    float b1vA = b1[lane], b1vB = b1vA;
    float b2vA = b2[lane], b2vB = b2vA;
    float w3vA = W3[lane], w3vB = w3vA;
    float b3vA = b3[0],    b3vB = b3vA;

    h2v w2rA[HH / 2], w2rB[HH / 2];  // (W2[lane][2k], W2[lane][2k+1])
    h2v w2cA[HH / 2], w2cB[HH / 2];  // (W2[2k][lane], W2[2k+1][lane])
#pragma unroll
    for (int k = 0; k < HH / 2; ++k) {
        h2v r = h2v{(_Float16)W2[lane * HH + 2 * k], (_Float16)W2[lane * HH + 2 * k + 1]};
        h2v c = h2v{(_Float16)W2[(2 * k) * HH + lane], (_Float16)W2[(2 * k + 1) * HH + lane]};
        w2rA[k] = r; w2rB[k] = r;
        w2cA[k] = c; w2cB[k] = c;
    }
    __syncthreads();  // one-time (staging); outside hot loop

    const float4* h1v4A = (const float4*)s_h1h[0];
    const float4* h1v4B = (const float4*)s_h1h[1];
    const float4* uv4A  = (const float4*)s_uh[0];
    const float4* uv4B  = (const float4*)s_uh[1];

    float t_prev = s_ts[0];
    const float x0A = s_xs[0][0];
    const float x0B = s_xs[1][0];
    float x_hatA = x0A, x_prevA = x0A;
    float x_hatB = x0B, x_prevB = x0B;
    if (lane == 0) { s_out[0][0] = x0A; s_out[1][0] = x0B; }

    float4 hrA[8], hrB[8];          // h1 pairs — live across phases
    float  h1fA, h2fA, predA, ulA, z1fA, sdz1A = 0.f;
    float  h1fB, h2fB, predB, ulB, z1fB, sdz1B = 0.f;
    float  tc = 0.f, tin = 0.f;
    float  x_trueA = 0.f, nlsA = 0.f;
    float  x_trueB = 0.f, nlsB = 0.f;

    // Two R12-exact merged phases (BWD of current pred + next FWD),
    // interleaved so each row's compute fills the other's LDS latency.
    auto MERGED2 = [&](float xtA, float xtB, bool final_) {
        // ---- backward scalar heads
        const float diffA = predA - xtA;
        const float dlA   = diffA + diffA;
        const float ndlA  = -LR * dlA;
        const float diffB = predB - xtB;
        const float dlB   = diffB + diffB;
        const float ndlB  = -LR * dlB;
        w3vA = fmaf(ndlA, h2fA, w3vA);  b3vA += ndlA;  b2vA = fmaf(ndlA, ulA, b2vA);
        w3vB = fmaf(ndlB, h2fB, w3vB);  b3vB += ndlB;  b2vB = fmaf(ndlB, ulB, b2vB);
        const _Float16 sdA = (_Float16)(ndlA * ulA);   const h2v sdvA = h2v{sdA, sdA};
        const _Float16 shA = (_Float16)(ndlA * h1fA);  const h2v shvA = h2v{shA, shA};
        const _Float16 sdB = (_Float16)(ndlB * ulB);   const h2v sdvB = h2v{sdB, sdB};
        const _Float16 shB = (_Float16)(ndlB * h1fB);  const h2v shvB = h2v{shB, shB};
        // ---- fused: d-dots on OLD w2c + w2c update (one u read), A/B per k
        float dA0 = 0.f, dA1 = 0.f, dA2 = 0.f, dA3 = 0.f;
        float dB0 = 0.f, dB1 = 0.f, dB2 = 0.f, dB3 = 0.f;
#pragma unroll
        for (int k = 0; k < 8; ++k) {
            float4 qa = uv4A[k];         // broadcast reads, both rows in flight
            float4 qb = uv4B[k];
            dA0 = FDOT2(w2cA[4 * k + 0], BC(qa.x), dA0);
            dA1 = FDOT2(w2cA[4 * k + 1], BC(qa.y), dA1);
            dA2 = FDOT2(w2cA[4 * k + 2], BC(qa.z), dA2);
            dA3 = FDOT2(w2cA[4 * k + 3], BC(qa.w), dA3);
            dB0 = FDOT2(w2cB[4 * k + 0], BC(qb.x), dB0);
            dB1 = FDOT2(w2cB[4 * k + 1], BC(qb.y), dB1);
            dB2 = FDOT2(w2cB[4 * k + 2], BC(qb.z), dB2);
            dB3 = FDOT2(w2cB[4 * k + 3], BC(qb.w), dB3);
            PKFMA(w2cA[4 * k + 0], shvA, BC(qa.x));
            PKFMA(w2cA[4 * k + 1], shvA, BC(qa.y));
            PKFMA(w2cA[4 * k + 2], shvA, BC(qa.z));
            PKFMA(w2cA[4 * k + 3], shvA, BC(qa.w));
            PKFMA(w2cB[4 * k + 0], shvB, BC(qb.x));
            PKFMA(w2cB[4 * k + 1], shvB, BC(qb.y));
            PKFMA(w2cB[4 * k + 2], shvB, BC(qb.z));
            PKFMA(w2cB[4 * k + 3], shvB, BC(qb.w));
        }
        const float rawA = (dA0 + dA1) + (dA2 + dA3);
        const float dh1A = dlA * rawA;
        const float dz1A = dh1A * fmaf(-h1fA, h1fA, 1.0f);
        sdz1A += dz1A;
        const float rawB = (dB0 + dB1) + (dB2 + dB3);
        const float dh1B = dlB * rawB;
        const float dz1B = dh1B * fmaf(-h1fB, h1fB, 1.0f);
        sdz1B += dz1B;
        // ---- next forward's z1 (+ materialization on the final phase)
        if (!final_) {
            z1fA = fmaf(nlsA, dz1A, z1fA);
            z1fB = fmaf(nlsB, dz1B, z1fB);
        } else {
            w1aA = fmaf(-LR * tc,      sdz1A, w1aA);
            w1bA = fmaf(-LR * x_prevA, sdz1A, w1bA);
            b1vA = fmaf(-LR,           sdz1A, b1vA);
            z1fA = fmaf(w1aA, tin, fmaf(w1bA, x_trueA, b1vA));
            w1aB = fmaf(-LR * tc,      sdz1B, w1aB);
            w1bB = fmaf(-LR * x_prevB, sdz1B, w1bB);
            b1vB = fmaf(-LR,           sdz1B, b1vB);
            z1fB = fmaf(w1aB, tin, fmaf(w1bB, x_trueB, b1vB));
        }
        h1fA = fast_tanh(z1fA);
        s_h1h[0][lane] = (_Float16)h1fA;
        h1fB = fast_tanh(z1fB);
        s_h1h[1][lane] = (_Float16)h1fB;
        // h1 write->read shadow: register-only w2r applies, both rows
#pragma unroll
        for (int k = 0; k < 8; ++k) {
            float4 oa = hrA[k];
            float4 ob = hrB[k];
            PKFMA(w2rA[4 * k + 0], sdvA, BC(oa.x));
            PKFMA(w2rA[4 * k + 1], sdvA, BC(oa.y));
            PKFMA(w2rA[4 * k + 2], sdvA, BC(oa.z));
            PKFMA(w2rA[4 * k + 3], sdvA, BC(oa.w));
            PKFMA(w2rB[4 * k + 0], sdvB, BC(ob.x));
            PKFMA(w2rB[4 * k + 1], sdvB, BC(ob.y));
            PKFMA(w2rB[4 * k + 2], sdvB, BC(ob.z));
            PKFMA(w2rB[4 * k + 3], sdvB, BC(ob.w));
        }
        // ---- forward a-dots on updated w2r, A/B per k
        float aA0 = b2vA, aA1 = 0.f, aA2 = 0.f, aA3 = 0.f;
        float aB0 = b2vB, aB1 = 0.f, aB2 = 0.f, aB3 = 0.f;
#pragma unroll
        for (int k = 0; k < 8; ++k) {
            float4 qa = h1v4A[k];
            float4 qb = h1v4B[k];
            hrA[k] = qa;                 // NEW h1 pairs
            hrB[k] = qb;
            aA0 = FDOT2(w2rA[4 * k + 0], BC(qa.x), aA0);
            aA1 = FDOT2(w2rA[4 * k + 1], BC(qa.y), aA1);
            aA2 = FDOT2(w2rA[4 * k + 2], BC(qa.z), aA2);
            aA3 = FDOT2(w2rA[4 * k + 3], BC(qa.w), aA3);
            aB0 = FDOT2(w2rB[4 * k + 0], BC(qb.x), aB0);
            aB1 = FDOT2(w2rB[4 * k + 1], BC(qb.y), aB1);
            aB2 = FDOT2(w2rB[4 * k + 2], BC(qb.z), aB2);
            aB3 = FDOT2(w2rB[4 * k + 3], BC(qb.w), aB3);
        }
        const float z2A = (aA0 + aA1) + (aA2 + aA3);
        h2fA = fast_tanh(z2A);
        const float ufA = w3vA * fmaf(-h2fA, h2fA, 1.0f);
        ulA = ufA;
        s_uh[0][lane] = (_Float16)ufA;
        const float z2B = (aB0 + aB1) + (aB2 + aB3);
        h2fB = fast_tanh(z2B);
        const float ufB = w3vB * fmaf(-h2fB, h2fB, 1.0f);
        ulB = ufB;
        s_uh[1][lane] = (_Float16)ufB;
        predA = wave_sum(w3vA * h2fA) + b3vA;
        predB = wave_sum(w3vB * h2fB) + b3vB;
    };

    // Pre-loop stash: theta0 forward at (ts[1], x0) = t=1's gs0 forward.
    z1fA = fmaf(w1aA, s_ts[1], fmaf(w1bA, x0A, b1vA));
    h1fA = fast_tanh(z1fA);
    s_h1h[0][lane] = (_Float16)h1fA;
    z1fB = fmaf(w1aB, s_ts[1], fmaf(w1bB, x0B, b1vB));
    h1fB = fast_tanh(z1fB);
    s_h1h[1][lane] = (_Float16)h1fB;
    {
        float aA0 = b2vA, aA1 = 0.f, aA2 = 0.f, aA3 = 0.f;
        float aB0 = b2vB, aB1 = 0.f, aB2 = 0.f, aB3 = 0.f;
#pragma unroll
        for (int k = 0; k < 8; ++k) {
            float4 qa = h1v4A[k];
            float4 qb = h1v4B[k];
            hrA[k] = qa;
            hrB[k] = qb;
            aA0 = FDOT2(w2rA[4 * k + 0], BC(qa.x), aA0);
            aA1 = FDOT2(w2rA[4 * k + 1], BC(qa.y), aA1);
            aA2 = FDOT2(w2rA[4 * k + 2], BC(qa.z), aA2);
            aA3 = FDOT2(w2rA[4 * k + 3], BC(qa.w), aA3);
            aB0 = FDOT2(w2rB[4 * k + 0], BC(qb.x), aB0);
            aB1 = FDOT2(w2rB[4 * k + 1], BC(qb.y), aB1);
            aB2 = FDOT2(w2rB[4 * k + 2], BC(qb.z), aB2);
            aB3 = FDOT2(w2rB[4 * k + 3], BC(qb.w), aB3);
        }
        const float z2A = (aA0 + aA1) + (aA2 + aA3);
        h2fA = fast_tanh(z2A);
        const float ufA = w3vA * fmaf(-h2fA, h2fA, 1.0f);
        ulA = ufA;
        s_uh[0][lane] = (_Float16)ufA;
        const float z2B = (aB0 + aB1) + (aB2 + aB3);
        h2fB = fast_tanh(z2B);
        const float ufB = w3vB * fmaf(-h2fB, h2fB, 1.0f);
        ulB = ufB;
        s_uh[1][lane] = (_Float16)ufB;
        predA = wave_sum(w3vA * h2fA) + b3vA;
        predB = wave_sum(w3vB * h2fB) + b3vB;
    }

    for (int t = 1; t < TT; ++t) {
        tc      = s_ts[t];
        tin     = tc + (tc - t_prev);
        x_trueA = s_xs[0][t];
        x_trueB = s_xs[1][t];
        nlsA = -LR * fmaf(tc, tc, fmaf(x_prevA, x_prevA, 1.0f));
        nlsB = -LR * fmaf(tc, tc, fmaf(x_prevB, x_prevB, 1.0f));
        const float x_tA = s_mask[0][t - 1] ? x_trueA : x_hatA;
        const float x_tB = s_mask[1][t - 1] ? x_trueB : x_hatB;

        sdz1A = 0.f;  sdz1B = 0.f;
        MERGED2(x_tA, x_tB, false);   // BWD gs0 + FWD gs1
        MERGED2(x_tA, x_tB, false);   // BWD gs1 + FWD gs2
        MERGED2(x_tA, x_tB, false);   // BWD gs2 + FWD gs3
        MERGED2(x_tA, x_tB, true);    // BWD gs3 + final forward
        x_hatA = predA;
        x_hatB = predB;

        if (lane == 0) { s_out[0][t] = x_hatA; s_out[1][t] = x_hatB; }
        t_prev  = tc;
        x_prevA = x_trueA;
        x_prevB = x_trueB;
    }

    // Coalesced flush of both rows' outputs (single wave: no barrier).
    for (int i = lane; i < TT; i += HH) {
        out[rowA * TT + i] = s_out[0][i];
        out[rowB * TT + i] = s_out[1][i];
    }
}

extern "C" void kernel_launch(void* const* d_in, const int* in_sizes, int n_in,
                              void* d_out, int out_size, void* d_ws, size_t ws_size,
                              hipStream_t stream) {
    const float* ts   = (const float*)d_in[0];
    const float* xs   = (const float*)d_in[1];
    const int*   mask = (const int*)d_in[2];
    const float* W1   = (const float*)d_in[3];
    const float* b1   = (const float*)d_in[4];
    const float* W2   = (const float*)d_in[5];
    const float* b2   = (const float*)d_in[6];
    const float* W3   = (const float*)d_in[7];
    const float* b3   = (const float*)d_in[8];
    float* out = (float*)d_out;

    const int B = in_sizes[1] / TT;  // 2048
    dim3 grid(B / 2), block(HH);
    hipLaunchKernelGGL(ttt_kernel, grid, block, 0, stream,
                       ts, xs, mask, W1, b1, W2, b2, W3, b3, out);
}

// Round 5
// 2600.552 us; speedup vs baseline: 1.3020x; 1.3020x over previous
//
#include <hip/hip_runtime.h>
#include <math.h>

// TTT recurrence: one wave (64 lanes) per row, lane = hidden index.
// R5: W2 as packed f16 pairs, v_dot2_f32_f16 matvecs, f16 LDS broadcasts.
// R7: fast_tanh (exp2+rcp), DPP wave reduction for the head.
// R8: no hot-loop barriers (single wave, DS in-order).
// R11: merged BWD->FWD phases, incremental z1.
// R12: u = w3*(1-h2^2) broadcast (dl factored), fused d-dots + w2c apply.
// R13 (reverted): readlane all-gather +29% -- LDS broadcast cheaper.
// R14/R15 (reverted): dual-row per wave +34% -- register pressure; and
// the p^2 stall arithmetic shows the 2 HW waves already interleave
// independently, so software dual-threading can't beat them.
// R16 (this): SOFTWARE-PIPELINED BROADCAST READS. Real issue occupancy is
// ~39% (VALUBusy's gfx94x formula is 4cyc/instr; true count ~190/phase);
// each wave stalls ~1550 cyc/phase, dominated by the two LDS write->read
// round trips whose reads issued only after wave_sum + loop head + scalar
// head had already run. Now: the 8 u-broadcast reads issue IMMEDIATELY
// after the u-write (end of phase k, data lands in U[] during wave_sum +
// loop head of phase k+1); the 8 h1-broadcast reads issue IMMEDIATELY
// after the h1-write into ping-pong H0/H1, with the 32-PKFMA w2r apply as
// fill before first use. Spine trims: 8-way dot accumulators (chain 8->4),
// k1=1-h1^2 off-spine, ns1=nls*2*diff*k1 prefold so raw->z1 is one fma.

#define TT  784
#define HH  64
#define LR  0.01f

typedef _Float16 h2v __attribute__((ext_vector_type(2)));
#define FDOT2(a, b, c) __builtin_amdgcn_fdot2((a), (b), (c), false)
#define BC(f) __builtin_bit_cast(h2v, (f))
#define PKFMA(acc, a, b) acc = __builtin_elementwise_fma((a), (b), (acc))

// tanh(x) = 1 - 2/(exp2(2*log2e*x)+1); saturates exactly at +-1.
__device__ __forceinline__ float fast_tanh(float x) {
    float e = __builtin_amdgcn_exp2f(x * 2.885390081777926814f);
    float r = __builtin_amdgcn_rcpf(e + 1.0f);
    return fmaf(-2.0f, r, 1.0f);
}

template <int CTRL, int RMASK, bool BC_>
__device__ __forceinline__ float dpp_add(float x) {
    int t = __builtin_amdgcn_update_dpp(0, __builtin_bit_cast(int, x),
                                        CTRL, RMASK, 0xf, BC_);
    return x + __builtin_bit_cast(float, t);
}

// Full wave64 sum -> uniform value (DPP reduce, total in lane 63).
__device__ __forceinline__ float wave_sum(float x) {
    x = dpp_add<0x111, 0xf, true>(x);   // row_shr:1
    x = dpp_add<0x112, 0xf, true>(x);   // row_shr:2
    x = dpp_add<0x114, 0xf, true>(x);   // row_shr:4
    x = dpp_add<0x118, 0xf, true>(x);   // row_shr:8
    x = dpp_add<0x142, 0xa, false>(x);  // row_bcast:15 -> rows 1,3
    x = dpp_add<0x143, 0xc, false>(x);  // row_bcast:31 -> rows 2,3
    return __builtin_bit_cast(float,
        __builtin_amdgcn_readlane(__builtin_bit_cast(int, x), 63));
}

__global__ __launch_bounds__(64, 2)
void ttt_kernel(const float* __restrict__ ts,
                const float* __restrict__ xs,
                const int*   __restrict__ mask,
                const float* __restrict__ W1,
                const float* __restrict__ b1,
                const float* __restrict__ W2,
                const float* __restrict__ b2,
                const float* __restrict__ W3,
                const float* __restrict__ b3,
                float* __restrict__ out)
{
    __shared__ __align__(16) _Float16 s_h1h[HH];   // h1 broadcast, f16
    __shared__ __align__(16) _Float16 s_uh[HH];    // u = w3*(1-h2^2), f16
    __shared__ float s_ts[TT];
    __shared__ float s_xs[TT];
    __shared__ float s_out[TT];
    __shared__ int   s_mask[TT - 1];

    const int row  = blockIdx.x;
    const int lane = threadIdx.x;  // 0..63

    for (int i = lane; i < TT; i += HH) {
        s_ts[i] = ts[i];
        s_xs[i] = xs[row * TT + i];
    }
    for (int i = lane; i < TT - 1; i += HH) s_mask[i] = mask[row * (TT - 1) + i];

    // Per-lane theta (f32 except W2 storage).
    float w1a = W1[2 * lane + 0];
    float w1b = W1[2 * lane + 1];
    float b1v = b1[lane];
    float b2v = b2[lane];
    float w3v = W3[lane];
    float b3v = b3[0];

    h2v w2r[HH / 2];  // (W2[lane][2k], W2[lane][2k+1])
    h2v w2c[HH / 2];  // (W2[2k][lane], W2[2k+1][lane])
#pragma unroll
    for (int k = 0; k < HH / 2; ++k) {
        w2r[k] = h2v{(_Float16)W2[lane * HH + 2 * k], (_Float16)W2[lane * HH + 2 * k + 1]};
        w2c[k] = h2v{(_Float16)W2[(2 * k) * HH + lane], (_Float16)W2[(2 * k + 1) * HH + lane]};
    }
    __syncthreads();  // one-time (staging); outside hot loop

    const float4* h1v4 = (const float4*)s_h1h;  // 8 float4 = 64 f16
    const float4* uv4  = (const float4*)s_uh;

    float t_prev = s_ts[0];
    const float x0 = s_xs[0];
    float x_hat  = x0;
    float x_prev = x0;
    if (lane == 0) s_out[0] = x0;

    float4 U[8];             // u broadcast pairs (pre-read at prev phase end)
    float4 H0[8], H1[8];     // h1 broadcast pairs, ping-pong across phases
    float  h1f, k1f, h2f, predf;  // own-lane h1, 1-h1^2, h2; uniform pred
    float  ul;               // own-lane u (f32 master copy)
    float  z1f;              // current z1 (incremental inside gs loop)
    float  sdz1 = 0.f;       // per-step sum of dz1
    float  tc = 0.f, x_true = 0.f, tin = 0.f, nls = 0.f;

    // Merged phase: BWD of the current pred, then the next forward.
    // hold = h1 pairs of the h1 that produced predf; hnew receives the new
    // h1 pairs (reads issued right after the write, apply as fill).
    // U[] is consumed by d-dots and refilled at the end for the NEXT phase.
    auto MERGED = [&](float4 (&hold)[8], float4 (&hnew)[8], float xt,
                      bool final_) {
        // ---- backward scalar head (off-spine; overlaps U's read latency)
        const float diff = predf - xt;
        const float ndl  = diff * (-2.0f * LR);       // -LR*dl
        const float s1   = (diff + diff) * k1f;       // dz1 = s1 * raw
        const float ns1  = nls * s1;                  // z1 += ns1 * raw
        w3v = fmaf(ndl, h2f, w3v);
        b3v += ndl;
        b2v = fmaf(ndl, ul, b2v);
        const _Float16 sd = (_Float16)(ndl * ul);     // -LR*dz2s (own lane)
        const h2v sdv = h2v{sd, sd};
        const _Float16 sh = (_Float16)(ndl * h1f);    // -LR*dl*h1_old
        const h2v shv = h2v{sh, sh};
        // ---- fused: d-dots on OLD w2c + w2c update (U already resident)
        float d0 = 0.f, d1 = 0.f, d2 = 0.f, d3 = 0.f;
        float d4 = 0.f, d5 = 0.f, d6 = 0.f, d7 = 0.f;
#pragma unroll
        for (int k = 0; k < 8; ++k) {
            const h2v q0 = BC(U[k].x), q1 = BC(U[k].y);
            const h2v q2 = BC(U[k].z), q3 = BC(U[k].w);
            if (k & 1) {
                d4 = FDOT2(w2c[4 * k + 0], q0, d4);
                d5 = FDOT2(w2c[4 * k + 1], q1, d5);
                d6 = FDOT2(w2c[4 * k + 2], q2, d6);
                d7 = FDOT2(w2c[4 * k + 3], q3, d7);
            } else {
                d0 = FDOT2(w2c[4 * k + 0], q0, d0);
                d1 = FDOT2(w2c[4 * k + 1], q1, d1);
                d2 = FDOT2(w2c[4 * k + 2], q2, d2);
                d3 = FDOT2(w2c[4 * k + 3], q3, d3);
            }
            PKFMA(w2c[4 * k + 0], shv, q0);
            PKFMA(w2c[4 * k + 1], shv, q1);
            PKFMA(w2c[4 * k + 2], shv, q2);
            PKFMA(w2c[4 * k + 3], shv, q3);
        }
        const float raw = ((d0 + d4) + (d1 + d5)) + ((d2 + d6) + (d3 + d7));
        // ---- next forward's z1 (+ materialization on the final phase)
        if (!final_) {
            sdz1 += s1 * raw;            // off-spine
            z1f = fmaf(ns1, raw, z1f);   // spine: one fma after raw
        } else {
            const float dz1 = s1 * raw;
            sdz1 += dz1;
            w1a = fmaf(-LR * tc,     sdz1, w1a);
            w1b = fmaf(-LR * x_prev, sdz1, w1b);
            b1v = fmaf(-LR,          sdz1, b1v);
            z1f = fmaf(w1a, tin, fmaf(w1b, x_true, b1v));
        }
        h1f = fast_tanh(z1f);
        s_h1h[lane] = (_Float16)h1f;
        // issue h1 broadcast reads NOW (in-order after the write)
#pragma unroll
        for (int k = 0; k < 8; ++k) hnew[k] = h1v4[k];
        k1f = fmaf(-h1f, h1f, 1.0f);     // off-spine (next phase's s1)
        // fill the h1 round trip: register-only w2r apply with OLD h1
#pragma unroll
        for (int k = 0; k < 8; ++k) {
            PKFMA(w2r[4 * k + 0], sdv, BC(hold[k].x));
            PKFMA(w2r[4 * k + 1], sdv, BC(hold[k].y));
            PKFMA(w2r[4 * k + 2], sdv, BC(hold[k].z));
            PKFMA(w2r[4 * k + 3], sdv, BC(hold[k].w));
        }
        // ---- forward a-dots on updated w2r, from hnew registers
        float a0 = b2v, a1 = 0.f, a2 = 0.f, a3 = 0.f;
        float a4 = 0.f, a5 = 0.f, a6 = 0.f, a7 = 0.f;
#pragma unroll
        for (int k = 0; k < 8; ++k) {
            const h2v q0 = BC(hnew[k].x), q1 = BC(hnew[k].y);
            const h2v q2 = BC(hnew[k].z), q3 = BC(hnew[k].w);
            if (k & 1) {
                a4 = FDOT2(w2r[4 * k + 0], q0, a4);
                a5 = FDOT2(w2r[4 * k + 1], q1, a5);
                a6 = FDOT2(w2r[4 * k + 2], q2, a6);
                a7 = FDOT2(w2r[4 * k + 3], q3, a7);
            } else {
                a0 = FDOT2(w2r[4 * k + 0], q0, a0);
                a1 = FDOT2(w2r[4 * k + 1], q1, a1);
                a2 = FDOT2(w2r[4 * k + 2], q2, a2);
                a3 = FDOT2(w2r[4 * k + 3], q3, a3);
            }
        }
        const float z2 = ((a0 + a4) + (a1 + a5)) + ((a2 + a6) + (a3 + a7));
        h2f = fast_tanh(z2);
        const float uf = w3v * fmaf(-h2f, h2f, 1.0f);
        ul = uf;
        s_uh[lane] = (_Float16)uf;
        // issue u broadcast reads NOW; wave_sum + loop/scalar head hide them
#pragma unroll
        for (int k = 0; k < 8; ++k) U[k] = uv4[k];
        predf = wave_sum(w3v * h2f) + b3v;
    };

    // Pre-loop stash: theta0 forward at (ts[1], x0) = t=1's gs0 forward.
    z1f = fmaf(w1a, s_ts[1], fmaf(w1b, x0, b1v));
    h1f = fast_tanh(z1f);
    k1f = fmaf(-h1f, h1f, 1.0f);
    s_h1h[lane] = (_Float16)h1f;
    {
#pragma unroll
        for (int k = 0; k < 8; ++k) H0[k] = h1v4[k];
        float a0 = b2v, a1 = 0.f, a2 = 0.f, a3 = 0.f;
        float a4 = 0.f, a5 = 0.f, a6 = 0.f, a7 = 0.f;
#pragma unroll
        for (int k = 0; k < 8; ++k) {
            const h2v q0 = BC(H0[k].x), q1 = BC(H0[k].y);
            const h2v q2 = BC(H0[k].z), q3 = BC(H0[k].w);
            if (k & 1) {
                a4 = FDOT2(w2r[4 * k + 0], q0, a4);
                a5 = FDOT2(w2r[4 * k + 1], q1, a5);
                a6 = FDOT2(w2r[4 * k + 2], q2, a6);
                a7 = FDOT2(w2r[4 * k + 3], q3, a7);
            } else {
                a0 = FDOT2(w2r[4 * k + 0], q0, a0);
                a1 = FDOT2(w2r[4 * k + 1], q1, a1);
                a2 = FDOT2(w2r[4 * k + 2], q2, a2);
                a3 = FDOT2(w2r[4 * k + 3], q3, a3);
            }
        }
        const float z2 = ((a0 + a4) + (a1 + a5)) + ((a2 + a6) + (a3 + a7));
        h2f = fast_tanh(z2);
        const float uf = w3v * fmaf(-h2f, h2f, 1.0f);
        ul = uf;
        s_uh[lane] = (_Float16)uf;
#pragma unroll
        for (int k = 0; k < 8; ++k) U[k] = uv4[k];
        predf = wave_sum(w3v * h2f) + b3v;
    }

    for (int t = 1; t < TT; ++t) {
        tc     = s_ts[t];
        x_true = s_xs[t];
        tin    = tc + (tc - t_prev);
        nls    = -LR * fmaf(tc, tc, fmaf(x_prev, x_prev, 1.0f));
        const float x_t = s_mask[t - 1] ? x_true : x_hat;   // teacher forcing

        sdz1 = 0.f;
        MERGED(H0, H1, x_t, false);   // BWD gs0 (stash fwd) + FWD gs1
        MERGED(H1, H0, x_t, false);   // BWD gs1 + FWD gs2
        MERGED(H0, H1, x_t, false);   // BWD gs2 + FWD gs3
        MERGED(H1, H0, x_t, true);    // BWD gs3 + final forward (next gs0)
        x_hat = predf;

        if (lane == 0) s_out[t] = x_hat;
        t_prev = tc;
        x_prev = x_true;
    }

    // Coalesced flush of the row's outputs (single wave: no barrier needed).
    for (int i = lane; i < TT; i += HH) out[row * TT + i] = s_out[i];
}

extern "C" void kernel_launch(void* const* d_in, const int* in_sizes, int n_in,
                              void* d_out, int out_size, void* d_ws, size_t ws_size,
                              hipStream_t stream) {
    const float* ts   = (const float*)d_in[0];
    const float* xs   = (const float*)d_in[1];
    const int*   mask = (const int*)d_in[2];
    const float* W1   = (const float*)d_in[3];
    const float* b1   = (const float*)d_in[4];
    const float* W2   = (const float*)d_in[5];
    const float* b2   = (const float*)d_in[6];
    const float* W3   = (const float*)d_in[7];
    const float* b3   = (const float*)d_in[8];
    float* out = (float*)d_out;

    const int B = in_sizes[1] / TT;  // 2048
    dim3 grid(B), block(HH);
    hipLaunchKernelGGL(ttt_kernel, grid, block, 0, stream,
                       ts, xs, mask, W1, b1, W2, b2, W3, b3, out);
}

// Round 7
// 2528.877 us; speedup vs baseline: 1.3389x; 1.0283x over previous
//
#include <hip/hip_runtime.h>
#include <math.h>

// TTT recurrence: one wave (64 lanes) per row, lane = hidden index.
// R5: W2 as packed f16 pairs, v_dot2_f32_f16 matvecs, f16 LDS broadcasts.
// R7: fast_tanh (exp2+rcp), DPP wave reduction for the head.
// R8: no hot-loop barriers (single wave, DS in-order).
// R11: merged BWD->FWD phases, incremental z1.
// R12: u = w3*(1-h2^2) broadcast (dl factored), fused d-dots + w2c apply.
// R13 (reverted): readlane all-gather +29% -- LDS broadcast cheaper.
// R14/R15 (reverted): dual-row per wave +34% -- occupancy halved.
// R16 (reverted): LDS-read prefetch +3% -- latency attacks keep failing.
// R17/R18 (this): REGISTER-ALLOCATOR EXPERIMENT. Issue-port model closes:
// wall 1919 cyc/phase/wave with VALUBusy 81.7% at 2cyc/instr = ~392 real
// VALU instr/phase vs ~200 at source level. Cross-checks: R13 +150 instr
// -> +556 cyc measured; R16 +25 -> +3%. The ~190 phantom instructions are
// suspected register-parking traffic (v_accvgpr_read/write or remat):
// VGPR_Count=92 vs ~150 live demand under the (64,2) occupancy heuristic.
// Change vs R12: __launch_bounds__(64, 1) -- the R14-proven spelling that
// lets the allocator allocate generously (168 there). Occupancy is
// grid-capped at 2 waves/SIMD regardless (2048 waves / 1024 SIMDs), and
// stays 2/SIMD while allocation <= 256 VGPRs. Structure otherwise
// R12-exact. (R17's amdgpu_waves_per_eu attribute resubmitted as this
// launch-bounds form after a second container-acquire flake.)

#define TT  784
#define HH  64
#define LR  0.01f

typedef _Float16 h2v __attribute__((ext_vector_type(2)));
#define FDOT2(a, b, c) __builtin_amdgcn_fdot2((a), (b), (c), false)
#define BC(f) __builtin_bit_cast(h2v, (f))
#define PKFMA(acc, a, b) acc = __builtin_elementwise_fma((a), (b), (acc))

// tanh(x) = 1 - 2/(exp2(2*log2e*x)+1); saturates exactly at +-1.
__device__ __forceinline__ float fast_tanh(float x) {
    float e = __builtin_amdgcn_exp2f(x * 2.885390081777926814f);
    float r = __builtin_amdgcn_rcpf(e + 1.0f);
    return fmaf(-2.0f, r, 1.0f);
}

template <int CTRL, int RMASK, bool BC_>
__device__ __forceinline__ float dpp_add(float x) {
    int t = __builtin_amdgcn_update_dpp(0, __builtin_bit_cast(int, x),
                                        CTRL, RMASK, 0xf, BC_);
    return x + __builtin_bit_cast(float, t);
}

// Full wave64 sum -> uniform value (DPP reduce, total in lane 63).
__device__ __forceinline__ float wave_sum(float x) {
    x = dpp_add<0x111, 0xf, true>(x);   // row_shr:1
    x = dpp_add<0x112, 0xf, true>(x);   // row_shr:2
    x = dpp_add<0x114, 0xf, true>(x);   // row_shr:4
    x = dpp_add<0x118, 0xf, true>(x);   // row_shr:8
    x = dpp_add<0x142, 0xa, false>(x);  // row_bcast:15 -> rows 1,3
    x = dpp_add<0x143, 0xc, false>(x);  // row_bcast:31 -> rows 2,3
    return __builtin_bit_cast(float,
        __builtin_amdgcn_readlane(__builtin_bit_cast(int, x), 63));
}

__global__ __launch_bounds__(64, 1)
void ttt_kernel(const float* __restrict__ ts,
                const float* __restrict__ xs,
                const int*   __restrict__ mask,
                const float* __restrict__ W1,
                const float* __restrict__ b1,
                const float* __restrict__ W2,
                const float* __restrict__ b2,
                const float* __restrict__ W3,
                const float* __restrict__ b3,
                float* __restrict__ out)
{
    __shared__ __align__(16) _Float16 s_h1h[HH];   // h1 broadcast, f16
    __shared__ __align__(16) _Float16 s_uh[HH];    // u = w3*(1-h2^2), f16
    __shared__ float s_ts[TT];
    __shared__ float s_xs[TT];
    __shared__ float s_out[TT];
    __shared__ int   s_mask[TT - 1];

    const int row  = blockIdx.x;
    const int lane = threadIdx.x;  // 0..63

    for (int i = lane; i < TT; i += HH) {
        s_ts[i] = ts[i];
        s_xs[i] = xs[row * TT + i];
    }
    for (int i = lane; i < TT - 1; i += HH) s_mask[i] = mask[row * (TT - 1) + i];

    // Per-lane theta (f32 except W2 storage).
    float w1a = W1[2 * lane + 0];
    float w1b = W1[2 * lane + 1];
    float b1v = b1[lane];
    float b2v = b2[lane];
    float w3v = W3[lane];
    float b3v = b3[0];

    h2v w2r[HH / 2];  // (W2[lane][2k], W2[lane][2k+1])
    h2v w2c[HH / 2];  // (W2[2k][lane], W2[2k+1][lane])
#pragma unroll
    for (int k = 0; k < HH / 2; ++k) {
        w2r[k] = h2v{(_Float16)W2[lane * HH + 2 * k], (_Float16)W2[lane * HH + 2 * k + 1]};
        w2c[k] = h2v{(_Float16)W2[(2 * k) * HH + lane], (_Float16)W2[(2 * k + 1) * HH + lane]};
    }
    __syncthreads();  // one-time (staging); outside hot loop

    const float4* h1v4 = (const float4*)s_h1h;  // 8 float4 = 64 f16
    const float4* uv4  = (const float4*)s_uh;

    float t_prev = s_ts[0];
    const float x0 = s_xs[0];
    float x_hat  = x0;
    float x_prev = x0;
    if (lane == 0) s_out[0] = x0;

    float4 hr[8];            // h1 pairs — live across phases
    float  h1f, h2f, predf;  // own-lane h1, h2; uniform pred
    float  ul;               // own-lane u (f32 master copy)
    float  z1f;              // current z1 (incremental inside gs loop)
    float  sdz1 = 0.f;       // per-step sum of dz1
    float  tc = 0.f, x_true = 0.f, tin = 0.f, nls = 0.f;

    // Merged phase: BWD of the current pred, then the next forward.
    auto MERGED = [&](float xt, bool final_) {
        // ---- backward scalar head
        const float diff = predf - xt;
        const float dl   = diff + diff;
        const float ndl  = -LR * dl;
        w3v = fmaf(ndl, h2f, w3v);       // OLD h2 (this backward's fwd)
        b3v += ndl;
        b2v = fmaf(ndl, ul, b2v);
        const _Float16 sd = (_Float16)(ndl * ul);     // -LR*dz2s (own lane)
        const h2v sdv = h2v{sd, sd};
        const _Float16 sh = (_Float16)(ndl * h1f);    // -LR*dl*h1_old
        const h2v shv = h2v{sh, sh};
        // ---- fused: d-dots on OLD w2c, then w2c update (one read of u)
        float d0 = 0.f, d1 = 0.f, d2 = 0.f, d3 = 0.f;
#pragma unroll
        for (int k = 0; k < 8; ++k) {
            float4 q = uv4[k];           // broadcast read (own-wave ordered)
            d0 = FDOT2(w2c[4 * k + 0], BC(q.x), d0);
            d1 = FDOT2(w2c[4 * k + 1], BC(q.y), d1);
            d2 = FDOT2(w2c[4 * k + 2], BC(q.z), d2);
            d3 = FDOT2(w2c[4 * k + 3], BC(q.w), d3);
            PKFMA(w2c[4 * k + 0], shv, BC(q.x));
            PKFMA(w2c[4 * k + 1], shv, BC(q.y));
            PKFMA(w2c[4 * k + 2], shv, BC(q.z));
            PKFMA(w2c[4 * k + 3], shv, BC(q.w));
        }
        const float raw = (d0 + d1) + (d2 + d3);
        const float dh1 = dl * raw;
        const float dz1 = dh1 * fmaf(-h1f, h1f, 1.0f);
        sdz1 += dz1;
        // ---- next forward's z1 (+ materialization on the final phase)
        if (!final_) {
            z1f = fmaf(nls, dz1, z1f);   // exact: inputs fixed over gs loop
        } else {
            w1a = fmaf(-LR * tc,     sdz1, w1a);
            w1b = fmaf(-LR * x_prev, sdz1, w1b);
            b1v = fmaf(-LR,          sdz1, b1v);
            z1f = fmaf(w1a, tin, fmaf(w1b, x_true, b1v));
        }
        h1f = fast_tanh(z1f);
        s_h1h[lane] = (_Float16)h1f;
        // h1 write->read shadow: register-only w2r apply (old hr, sdv)
#pragma unroll
        for (int k = 0; k < 8; ++k) {
            float4 o = hr[k];            // OLD h1 pairs (register-resident)
            PKFMA(w2r[4 * k + 0], sdv, BC(o.x));
            PKFMA(w2r[4 * k + 1], sdv, BC(o.y));
            PKFMA(w2r[4 * k + 2], sdv, BC(o.z));
            PKFMA(w2r[4 * k + 3], sdv, BC(o.w));
        }
        // ---- forward a-dots on updated w2r
        float a0 = b2v, a1 = 0.f, a2 = 0.f, a3 = 0.f;
#pragma unroll
        for (int k = 0; k < 8; ++k) {
            float4 q = h1v4[k];          // broadcast read
            hr[k] = q;                   // NEW h1 pairs
            a0 = FDOT2(w2r[4 * k + 0], BC(q.x), a0);
            a1 = FDOT2(w2r[4 * k + 1], BC(q.y), a1);
            a2 = FDOT2(w2r[4 * k + 2], BC(q.z), a2);
            a3 = FDOT2(w2r[4 * k + 3], BC(q.w), a3);
        }
        const float z2 = (a0 + a1) + (a2 + a3);
        h2f = fast_tanh(z2);
        const float uf = w3v * fmaf(-h2f, h2f, 1.0f);
        ul = uf;
        s_uh[lane] = (_Float16)uf;
        predf = wave_sum(w3v * h2f) + b3v;
    };

    // Pre-loop stash: theta0 forward at (ts[1], x0) = t=1's gs0 forward.
    z1f = fmaf(w1a, s_ts[1], fmaf(w1b, x0, b1v));
    h1f = fast_tanh(z1f);
    s_h1h[lane] = (_Float16)h1f;
    {
        float a0 = b2v, a1 = 0.f, a2 = 0.f, a3 = 0.f;
#pragma unroll
        for (int k = 0; k < 8; ++k) {
            float4 q = h1v4[k];
            hr[k] = q;
            a0 = FDOT2(w2r[4 * k + 0], BC(q.x), a0);
            a1 = FDOT2(w2r[4 * k + 1], BC(q.y), a1);
            a2 = FDOT2(w2r[4 * k + 2], BC(q.z), a2);
            a3 = FDOT2(w2r[4 * k + 3], BC(q.w), a3);
        }
        const float z2 = (a0 + a1) + (a2 + a3);
        h2f = fast_tanh(z2);
        const float uf = w3v * fmaf(-h2f, h2f, 1.0f);
        ul = uf;
        s_uh[lane] = (_Float16)uf;
        predf = wave_sum(w3v * h2f) + b3v;
    }

    for (int t = 1; t < TT; ++t) {
        tc     = s_ts[t];
        x_true = s_xs[t];
        tin    = tc + (tc - t_prev);
        nls    = -LR * fmaf(tc, tc, fmaf(x_prev, x_prev, 1.0f));
        const float x_t = s_mask[t - 1] ? x_true : x_hat;   // teacher forcing

        sdz1 = 0.f;
        MERGED(x_t, false);   // BWD gs0 (stash fwd) + FWD gs1
        MERGED(x_t, false);   // BWD gs1 + FWD gs2
        MERGED(x_t, false);   // BWD gs2 + FWD gs3
        MERGED(x_t, true);    // BWD gs3 + final forward (t+1's gs0 stash)
        x_hat = predf;

        if (lane == 0) s_out[t] = x_hat;
        t_prev = tc;
        x_prev = x_true;
    }

    // Coalesced flush of the row's outputs (single wave: no barrier needed).
    for (int i = lane; i < TT; i += HH) out[row * TT + i] = s_out[i];
}

extern "C" void kernel_launch(void* const* d_in, const int* in_sizes, int n_in,
                              void* d_out, int out_size, void* d_ws, size_t ws_size,
                              hipStream_t stream) {
    const float* ts   = (const float*)d_in[0];
    const float* xs   = (const float*)d_in[1];
    const int*   mask = (const int*)d_in[2];
    const float* W1   = (const float*)d_in[3];
    const float* b1   = (const float*)d_in[4];
    const float* W2   = (const float*)d_in[5];
    const float* b2   = (const float*)d_in[6];
    const float* W3   = (const float*)d_in[7];
    const float* b3   = (const float*)d_in[8];
    float* out = (float*)d_out;

    const int B = in_sizes[1] / TT;  // 2048
    dim3 grid(B), block(HH);
    hipLaunchKernelGGL(ttt_kernel, grid, block, 0, stream,
                       ts, xs, mask, W1, b1, W2, b2, W3, b3, out);
}